// Round 3
// baseline (2361.309 us; speedup 1.0000x reference)
//
#include <hip/hip_runtime.h>
#include <hip/hip_bf16.h>
#include <stddef.h>

#define DEVINL __device__ __forceinline__

typedef __attribute__((ext_vector_type(8))) short short8;
typedef __attribute__((ext_vector_type(4))) float f32x4;

static constexpr int S_LEN = 2048;
static constexpr int C_LEN = 2048;
static constexpr int DMODEL = 768;
static constexpr int NHEAD = 12;
static constexpr int DHEAD = 64;
static constexpr float SCALE = 0.125f;   // 1/sqrt(64)

// ---------- bf16 helpers (bit-level, RNE) ----------
DEVINL float bf2f(short s) {
    union { unsigned u; float f; } v;
    v.u = ((unsigned)(unsigned short)s) << 16;
    return v.f;
}
DEVINL short f2bf(float f) {
    union { float f; unsigned u; } v;
    v.f = f;
    unsigned r = v.u + 0x7FFFu + ((v.u >> 16) & 1u);
    return (short)(r >> 16);
}
DEVINL f32x4 zero4() { f32x4 z; z[0]=0.f; z[1]=0.f; z[2]=0.f; z[3]=0.f; return z; }

// ---------- LDS staging: [ROWS][WIDTH] bf16 tile, 16B chunks, 256 threads ----------
template<int ROWS, int WIDTH>
DEVINL void stage_tile(short* dst, const short* src, int src_stride) {
    constexpr int CPR = WIDTH / 8;           // 16B chunks per row
    constexpr int CH  = ROWS * CPR;
    for (int c = threadIdx.x; c < CH; c += 256) {
        int row = c / CPR;
        int cc  = (c % CPR) * 8;
        *(int4*)(dst + row * WIDTH + cc) = *(const int4*)(src + (size_t)row * src_stride + cc);
    }
}

// ---------- LDS staging with elementwise product: dst[r][c] = a[r][c]*b[r][c], 64x64 bf16 ----------
DEVINL void stage_mul64(short* dst, const short* asrc, const short* bsrc) {
    for (int c = threadIdx.x; c < 512; c += 256) {
        int row = c >> 3;
        int cc  = (c & 7) * 8;
        short8 a = *(const short8*)(asrc + (size_t)row * DMODEL + cc);
        short8 b = *(const short8*)(bsrc + (size_t)row * DMODEL + cc);
        short8 r;
#pragma unroll
        for (int e = 0; e < 8; ++e) r[e] = f2bf(bf2f(a[e]) * bf2f(b[e]));
        *(short8*)(dst + row * 64 + cc) = r;
    }
}

// ---------- one BK=64 MFMA step for a 128x128 tile, 4 waves in 2x2 of 64x64 ----------
DEVINL void mfma_step_128(const short* As, const short* Bs, f32x4 acc[4][4],
                          int wr, int wc, int lane) {
#pragma unroll
    for (int kk = 0; kk < 64; kk += 32) {
        short8 a[4], b[4];
#pragma unroll
        for (int mi = 0; mi < 4; ++mi)
            a[mi] = *(const short8*)(As + (wr*64 + mi*16 + (lane & 15)) * 64 + kk + (lane >> 4) * 8);
#pragma unroll
        for (int ni = 0; ni < 4; ++ni)
            b[ni] = *(const short8*)(Bs + (wc*64 + ni*16 + (lane & 15)) * 64 + kk + (lane >> 4) * 8);
#pragma unroll
        for (int mi = 0; mi < 4; ++mi)
#pragma unroll
            for (int ni = 0; ni < 4; ++ni)
                acc[mi][ni] = __builtin_amdgcn_mfma_f32_16x16x32_bf16(a[mi], b[ni], acc[mi][ni], 0, 0, 0);
    }
}

// ---------- one BK=64 MFMA step: wave computes 16 rows x 128 cols ----------
DEVINL void mfma_row16(const short* As, const short* Bs, f32x4 acc[8], int w, int lane) {
#pragma unroll
    for (int kk = 0; kk < 64; kk += 32) {
        short8 a = *(const short8*)(As + (w*16 + (lane & 15)) * 64 + kk + (lane >> 4) * 8);
#pragma unroll
        for (int nj = 0; nj < 8; ++nj) {
            short8 b = *(const short8*)(Bs + (nj*16 + (lane & 15)) * 64 + kk + (lane >> 4) * 8);
            acc[nj] = __builtin_amdgcn_mfma_f32_16x16x32_bf16(a, b, acc[nj], 0, 0, 0);
        }
    }
}

// ---------- shared 128x128 TN GEMM body (both strides 768, bf16 srcs) ----------
template<int KSTEPS>
DEVINL void gemm128_body(const short* A, const short* Bt, short* As, short* Bs,
                         f32x4 acc[4][4], int wr, int wc, int lane) {
    for (int ks = 0; ks < KSTEPS; ++ks) {
        if (ks) __syncthreads();
        stage_tile<128, 64>(As, A + ks * 64, DMODEL);
        stage_tile<128, 64>(Bs, Bt + ks * 64, DMODEL);
        __syncthreads();
        mfma_step_128(As, Bs, acc, wr, wc, lane);
    }
}

// ================= kernel A: f32 -> bf16 convert (8 streams via blockIdx.z) =================
__global__ void conv_kernel(const float* q, const float* k, const float* v,
                            const float* phi, const float* pi_, const float* psi,
                            const float* omega, const float* rk,
                            short* qc, short* kc, short* vc,
                            short* phc, short* pic, short* psc, short* omc, short* rkc) {
    int z = blockIdx.z;
    const float* src; short* dst; int n4;     // n4 = element count / 4
    switch (z) {
        case 0: src = q;     dst = qc;  n4 = 393216; break;
        case 1: src = k;     dst = kc;  n4 = 393216; break;
        case 2: src = v;     dst = vc;  n4 = 393216; break;
        case 3: src = phi;   dst = phc; n4 = 393216; break;
        case 4: src = pi_;   dst = pic; n4 = 393216; break;
        case 5: src = psi;   dst = psc; n4 = 393216; break;
        case 6: src = omega; dst = omc; n4 = 393216; break;
        default: src = rk;   dst = rkc; n4 = 147456; break;
    }
    for (int i = blockIdx.x * 256 + threadIdx.x; i < n4; i += gridDim.x * 256) {
        float4 f = *(const float4*)(src + (size_t)i * 4);
        short4 o;
        o.x = f2bf(f.x); o.y = f2bf(f.y); o.z = f2bf(f.z); o.w = f2bf(f.w);
        *(short4*)(dst + (size_t)i * 4) = o;
    }
}

// ================= kernel 0: transpose the 768x768 weights (f32 -> bf16^T) =================
__global__ void transpose_kernel(const float* wq, const float* wk, const float* wv, const float* wo,
                                 short* wqt, short* wkt, short* wvt, short* wot) {
    __shared__ float tile[64][65];
    int z = blockIdx.z;
    const float* src = (z == 0) ? wq : (z == 1) ? wk : (z == 2) ? wv : wo;
    short*       dst = (z == 0) ? wqt : (z == 1) ? wkt : (z == 2) ? wvt : wot;
    int r0 = blockIdx.x * 64, c0 = blockIdx.y * 64;
    for (int e = threadIdx.x; e < 4096; e += 256) {
        int rr = e >> 6, cc = e & 63;
        tile[rr][cc] = src[(size_t)(r0 + rr) * DMODEL + c0 + cc];
    }
    __syncthreads();
    for (int e = threadIdx.x; e < 4096; e += 256) {
        int rr = e >> 6, cc = e & 63;
        dst[(size_t)(c0 + rr) * DMODEL + r0 + cc] = f2bf(tile[cc][rr]);
    }
}

// ================= kernel 1: Q/K/V projections =================
__global__ __launch_bounds__(256, 2)
void qkv_kernel(const short* qc, const short* kc, const short* vc,
                const short* wqt, const short* wkt, const short* wvt,
                const float* bk, const float* bv,
                const float* rw, const float* rr, const float* rs,
                short* qw_a, short* qr_hat, short* qs_hat, short* kpack, short* vt) {
    __shared__ short As[128 * 64], Bs[128 * 64];
    int z = blockIdx.z;
    const short* A  = (z == 0) ? qc  : (z == 1) ? kc  : vc;
    const short* Bt = (z == 0) ? wqt : (z == 1) ? wkt : wvt;
    int i0 = blockIdx.x * 128, c0 = blockIdx.y * 128;
    int t = threadIdx.x, lane = t & 63, w = t >> 6, wr = w >> 1, wc = w & 1;

    f32x4 acc[4][4];
#pragma unroll
    for (int mi = 0; mi < 4; ++mi)
#pragma unroll
        for (int ni = 0; ni < 4; ++ni) acc[mi][ni] = zero4();

    gemm128_body<12>(A + (size_t)i0 * DMODEL, Bt + (size_t)c0 * DMODEL, As, Bs, acc, wr, wc, lane);

#pragma unroll
    for (int mi = 0; mi < 4; ++mi)
#pragma unroll
        for (int ni = 0; ni < 4; ++ni)
#pragma unroll
            for (int r = 0; r < 4; ++r) {
                int row = i0 + wr*64 + mi*16 + ((lane >> 4) << 2) + r;
                int col = c0 + wc*64 + ni*16 + (lane & 15);
                float v = acc[mi][ni][r];
                if (z == 0) {
                    v *= SCALE;
                    size_t o = (size_t)row * DMODEL + col;
                    qw_a[o]   = f2bf(v + rw[col] * SCALE);
                    qr_hat[o] = f2bf(v + rr[col] * SCALE);
                    qs_hat[o] = f2bf(v + rs[col] * SCALE);
                } else if (z == 1) {
                    float vv = v + bk[col];
                    kpack[((size_t)(col >> 6) * C_LEN + row) * DHEAD + (col & 63)] = f2bf(vv);
                } else {
                    float vv = v + bv[col];
                    vt[((size_t)(col >> 6) * DHEAD + (col & 63)) * C_LEN + row] = f2bf(vv);
                }
            }
}

// ================= kernel 2: qr slab for a 6-head chunk =================
__global__ __launch_bounds__(256, 2)
void qr_kernel(const short* qr_hat, const short* rkc, short* qr, int n_base) {
    __shared__ short As[128 * 64], Bs[128 * 64];
    int nl = blockIdx.z, n = n_base + nl;
    int i0 = blockIdx.x * 128, d0 = blockIdx.y * 128;
    int t = threadIdx.x, lane = t & 63, w = t >> 6, wr = w >> 1, wc = w & 1;

    f32x4 acc[4][4];
#pragma unroll
    for (int mi = 0; mi < 4; ++mi)
#pragma unroll
        for (int ni = 0; ni < 4; ++ni) acc[mi][ni] = zero4();

    gemm128_body<1>(qr_hat + (size_t)i0 * DMODEL + n * DHEAD,
                    rkc + (size_t)d0 * DMODEL + n * DHEAD,
                    As, Bs, acc, wr, wc, lane);

#pragma unroll
    for (int mi = 0; mi < 4; ++mi)
#pragma unroll
        for (int ni = 0; ni < 4; ++ni)
#pragma unroll
            for (int r = 0; r < 4; ++r) {
                int row = i0 + wr*64 + mi*16 + ((lane >> 4) << 2) + r;   // i
                int col = d0 + wc*64 + ni*16 + (lane & 15);              // d
                qr[((size_t)nl * S_LEN + row) * DMODEL + col] = f2bf(acc[mi][ni][r]);
            }
}

// ================= kernel 2b: token-type bias =================
__global__ void ttb_kernel(const short* qs_hat, const float* seg, float* ttd, float* tts) {
    int idx = blockIdx.x * 256 + threadIdx.x;       // 12*2048 total
    int n = idx >> 11, i = idx & 2047;
    const short* q  = qs_hat + (size_t)i * DMODEL + n * DHEAD;
    const float* e0 = seg + n * DHEAD;              // seg[0][n][:]
    const float* e1 = seg + NHEAD * DHEAD + n * DHEAD;
    float s0 = 0.f, s1 = 0.f;
#pragma unroll
    for (int h = 0; h < DHEAD; ++h) {
        float qv = bf2f(q[h]);
        s0 += qv * e0[h];
        s1 += qv * e1[h];
    }
    ttd[n * S_LEN + i] = s0;
    tts[n * S_LEN + i] = s1;
}

// ================= kernel 3: fused score + softmax + PV (flash) =================
__global__ __launch_bounds__(256, 2)
void flash_kernel(const short* qw_a, const short* kpack, const short* qr,
                  const short* phc, const short* pic,
                  const short* psc, const short* omc, const float* cls_mask,
                  const int* ttmat, const int* amask, const float* ttd, const float* tts,
                  const short* vt, short* avec, int n_base) {
    __shared__ short As[64 * 64];
    __shared__ short Bs[128 * 64];
    __shared__ short Ps[64 * 128];
    __shared__ short Bv[64 * 128];

    int nl = blockIdx.y, n = n_base + nl;
    int i0 = blockIdx.x * 64;
    int t = threadIdx.x, lane = t & 63, w = t >> 6;
    int lrow = lane >> 4;       // 0..3
    int lcol = lane & 15;       // 0..15

    f32x4 out_acc[4];
    float m[4], l[4];
#pragma unroll
    for (int x = 0; x < 4; ++x) { out_acc[x] = zero4(); m[x] = -1.0e9f; l[x] = 0.f; }

    for (int jt = 0; jt < 16; ++jt) {
        int j0 = jt * 128;
        f32x4 acc_c[8], acc_p[8];
#pragma unroll
        for (int nj = 0; nj < 8; ++nj) { acc_c[nj] = zero4(); acc_p[nj] = zero4(); }

        // ---- content step (K = 64) ----
        __syncthreads();
        stage_tile<64, 64>(As, qw_a + (size_t)i0 * DMODEL + n * DHEAD, DMODEL);
        stage_tile<128, 64>(Bs, kpack + ((size_t)n * C_LEN + j0) * DHEAD, DHEAD);
        __syncthreads();
        mfma_row16(As, Bs, acc_c, w, lane);

        // ---- pos steps (K = 768 x {phi/psi} then {pi/omega}) ----
        for (int ks = 0; ks < 24; ++ks) {
            int d0 = (ks % 12) * 64;
            const short* qsrc = qr + ((size_t)nl * S_LEN + i0) * DMODEL + d0;
            const short* fsrc = ((ks < 12) ? phc : pic) + (size_t)i0 * DMODEL + d0;
            const short* bsrc = ((ks < 12) ? psc : omc) + (size_t)j0 * DMODEL + d0;
            __syncthreads();
            stage_mul64(As, qsrc, fsrc);
            stage_tile<128, 64>(Bs, bsrc, DMODEL);
            __syncthreads();
            mfma_row16(As, Bs, acc_p, w, lane);
        }

        // ---- epilogue: combine + online softmax ----
        int iBase = i0 + w*16 + lrow*4;
        float tdiff[4], tsame[4];
#pragma unroll
        for (int r = 0; r < 4; ++r) {
            tdiff[r] = ttd[n * S_LEN + iBase + r];
            tsame[r] = tts[n * S_LEN + iBase + r];
        }
        float pbuf[8][4];
        float tmax[4] = { -1.0e9f, -1.0e9f, -1.0e9f, -1.0e9f };
#pragma unroll
        for (int nj = 0; nj < 8; ++nj) {
            int jg = j0 + nj*16 + lcol;
            float pen = 1.0e6f * (1.0f - (float)amask[jg]);
#pragma unroll
            for (int r = 0; r < 4; ++r) {
                size_t eidx = (size_t)(iBase + r) * C_LEN + jg;
                float clsv = cls_mask[eidx];
                float ttv  = ttmat[eidx] ? tsame[r] : tdiff[r];
                float sc = acc_c[nj][r] + clsv * (acc_p[nj][r] + ttv) - pen;
                pbuf[nj][r] = sc;
                tmax[r] = fmaxf(tmax[r], sc);
            }
        }
        float alph[4];
#pragma unroll
        for (int r = 0; r < 4; ++r) {
            float v = tmax[r];
            v = fmaxf(v, __shfl_xor(v, 1));
            v = fmaxf(v, __shfl_xor(v, 2));
            v = fmaxf(v, __shfl_xor(v, 4));
            v = fmaxf(v, __shfl_xor(v, 8));
            float mn = fmaxf(m[r], v);
            alph[r] = __expf(fminf(m[r] - mn, 0.0f));
            m[r] = mn;
        }
        float rsum[4] = { 0.f, 0.f, 0.f, 0.f };
#pragma unroll
        for (int nj = 0; nj < 8; ++nj)
#pragma unroll
            for (int r = 0; r < 4; ++r) {
                float pv = __expf(fminf(pbuf[nj][r] - m[r], 0.0f));
                pbuf[nj][r] = pv;
                rsum[r] += pv;
            }
#pragma unroll
        for (int r = 0; r < 4; ++r) {
            float v = rsum[r];
            v += __shfl_xor(v, 1);
            v += __shfl_xor(v, 2);
            v += __shfl_xor(v, 4);
            v += __shfl_xor(v, 8);
            l[r] = l[r] * alph[r] + v;
        }
#pragma unroll
        for (int nh = 0; nh < 4; ++nh)
#pragma unroll
            for (int r = 0; r < 4; ++r) out_acc[nh][r] *= alph[r];

        // write P tile (bf16) to LDS
#pragma unroll
        for (int nj = 0; nj < 8; ++nj)
#pragma unroll
            for (int r = 0; r < 4; ++r)
                Ps[(w*16 + lrow*4 + r) * 128 + nj*16 + lcol] = f2bf(pbuf[nj][r]);

        // stage V^T tile [64 h][128 j]
        stage_tile<64, 128>(Bv, vt + (size_t)(n * DHEAD) * C_LEN + j0, C_LEN);
        __syncthreads();

        // ---- PV accumulate (K = 128) ----
#pragma unroll
        for (int kk = 0; kk < 4; ++kk) {
            short8 pa = *(const short8*)(Ps + (w*16 + lcol) * 128 + kk*32 + lrow*8);
#pragma unroll
            for (int nh = 0; nh < 4; ++nh) {
                short8 vb = *(const short8*)(Bv + (nh*16 + lcol) * 128 + kk*32 + lrow*8);
                out_acc[nh] = __builtin_amdgcn_mfma_f32_16x16x32_bf16(pa, vb, out_acc[nh], 0, 0, 0);
            }
        }
    }

    // ---- final normalize + write ----
#pragma unroll
    for (int nh = 0; nh < 4; ++nh)
#pragma unroll
        for (int r = 0; r < 4; ++r) {
            int ig = i0 + w*16 + lrow*4 + r;
            int h  = nh*16 + lcol;
            avec[(size_t)ig * DMODEL + n * DHEAD + h] = f2bf(out_acc[nh][r] / l[r]);
        }
}

// ================= kernel 4: output projection + bias + residual =================
__global__ __launch_bounds__(256, 2)
void outproj_kernel(const short* avec, const short* wot, const float* bo,
                    const float* query, float* X) {
    __shared__ short As[128 * 64], Bs[128 * 64];
    int i0 = blockIdx.x * 128, c0 = blockIdx.y * 128;
    int t = threadIdx.x, lane = t & 63, w = t >> 6, wr = w >> 1, wc = w & 1;

    f32x4 acc[4][4];
#pragma unroll
    for (int mi = 0; mi < 4; ++mi)
#pragma unroll
        for (int ni = 0; ni < 4; ++ni) acc[mi][ni] = zero4();

    gemm128_body<12>(avec + (size_t)i0 * DMODEL, wot + (size_t)c0 * DMODEL, As, Bs, acc, wr, wc, lane);

#pragma unroll
    for (int mi = 0; mi < 4; ++mi)
#pragma unroll
        for (int ni = 0; ni < 4; ++ni)
#pragma unroll
            for (int r = 0; r < 4; ++r) {
                int row = i0 + wr*64 + mi*16 + ((lane >> 4) << 2) + r;
                int col = c0 + wc*64 + ni*16 + (lane & 15);
                float v = acc[mi][ni][r] + bo[col];
                X[(size_t)row * DMODEL + col] = v + query[(size_t)row * DMODEL + col];
            }
}

// ================= kernel 5: layernorm (f32 in, f32 out) =================
__global__ void ln_kernel(const float* X, const float* gam, const float* bet, float* out) {
    int row = blockIdx.x, t = threadIdx.x;
    const float* xr = X + (size_t)row * DMODEL;
    float x0 = xr[t], x1 = xr[t + 256], x2 = xr[t + 512];
    float s = x0 + x1 + x2;
    float q = x0*x0 + x1*x1 + x2*x2;
#pragma unroll
    for (int d = 1; d < 64; d <<= 1) { s += __shfl_xor(s, d); q += __shfl_xor(q, d); }
    __shared__ float rs_[4], rq_[4];
    int w = t >> 6, lane = t & 63;
    if (lane == 0) { rs_[w] = s; rq_[w] = q; }
    __syncthreads();
    s = rs_[0] + rs_[1] + rs_[2] + rs_[3];
    q = rq_[0] + rq_[1] + rq_[2] + rq_[3];
    float mu  = s * (1.0f / 768.0f);
    float var = q * (1.0f / 768.0f) - mu * mu;
    float rstd = rsqrtf(fmaxf(var, 0.0f) + 1e-9f);
    out[(size_t)row * DMODEL + t]       = (x0 - mu) * rstd * gam[t]       + bet[t];
    out[(size_t)row * DMODEL + t + 256] = (x1 - mu) * rstd * gam[t + 256] + bet[t + 256];
    out[(size_t)row * DMODEL + t + 512] = (x2 - mu) * rstd * gam[t + 512] + bet[t + 512];
}

// ================= launch =================
extern "C" void kernel_launch(void* const* d_in, const int* in_sizes, int n_in,
                              void* d_out, int out_size, void* d_ws, size_t ws_size,
                              hipStream_t stream) {
    const float* query = (const float*)d_in[0];
    const float* key   = (const float*)d_in[1];
    const float* value = (const float*)d_in[2];
    const float* phi   = (const float*)d_in[3];
    const float* pi_   = (const float*)d_in[4];
    const float* psi   = (const float*)d_in[5];
    const float* omega = (const float*)d_in[6];
    const float* cls   = (const float*)d_in[7];
    const int*   ttm   = (const int*)d_in[8];
    const int*   am    = (const int*)d_in[9];
    const float* Wq    = (const float*)d_in[10];
    const float* Wk    = (const float*)d_in[11];
    const float* bk    = (const float*)d_in[12];
    const float* Wv    = (const float*)d_in[13];
    const float* bv    = (const float*)d_in[14];
    const float* rw    = (const float*)d_in[15];
    const float* rr    = (const float*)d_in[16];
    const float* rk    = (const float*)d_in[17];
    const float* rs    = (const float*)d_in[18];
    const float* seg   = (const float*)d_in[19];
    const float* Wo    = (const float*)d_in[20];
    const float* bo    = (const float*)d_in[21];
    const float* lng   = (const float*)d_in[22];
    const float* lnb   = (const float*)d_in[23];

    char* ws = (char*)d_ws;
    constexpr size_t SZ_W   = 768ull * 768 * 2;
    constexpr size_t SZ_SD  = 2048ull * 768 * 2;
    constexpr size_t OFF_WQT = 0;
    constexpr size_t OFF_WKT = OFF_WQT + SZ_W;
    constexpr size_t OFF_WVT = OFF_WKT + SZ_W;
    constexpr size_t OFF_WOT = OFF_WVT + SZ_W;
    constexpr size_t OFF_RKC = OFF_WOT + SZ_W;
    constexpr size_t OFF_QC  = OFF_RKC + SZ_W;
    constexpr size_t OFF_KC  = OFF_QC  + SZ_SD;
    constexpr size_t OFF_VC  = OFF_KC  + SZ_SD;
    constexpr size_t OFF_PHC = OFF_VC  + SZ_SD;
    constexpr size_t OFF_PIC = OFF_PHC + SZ_SD;
    constexpr size_t OFF_PSC = OFF_PIC + SZ_SD;
    constexpr size_t OFF_OMC = OFF_PSC + SZ_SD;
    constexpr size_t OFF_QWA = OFF_OMC + SZ_SD;
    constexpr size_t OFF_QRH = OFF_QWA + SZ_SD;
    constexpr size_t OFF_QSH = OFF_QRH + SZ_SD;
    constexpr size_t OFF_KP  = OFF_QSH + SZ_SD;
    constexpr size_t OFF_VT  = OFF_KP  + SZ_SD;
    constexpr size_t OFF_QR  = OFF_VT  + SZ_SD;                 // 6-head slab
    constexpr size_t OFF_TTD = OFF_QR  + 6ull * 2048 * 768 * 2;
    constexpr size_t OFF_TTS = OFF_TTD + 12ull * 2048 * 4;
    constexpr size_t OFF_AV  = OFF_TTS + 12ull * 2048 * 4;
    constexpr size_t OFF_X   = OFF_AV  + SZ_SD;
    constexpr size_t NEED    = OFF_X + 2048ull * 768 * 4;

    if (ws_size < NEED) return;   // diagnostic: leaves d_out untouched

    short* wqt  = (short*)(ws + OFF_WQT);
    short* wkt  = (short*)(ws + OFF_WKT);
    short* wvt  = (short*)(ws + OFF_WVT);
    short* wot  = (short*)(ws + OFF_WOT);
    short* rkc  = (short*)(ws + OFF_RKC);
    short* qc   = (short*)(ws + OFF_QC);
    short* kc   = (short*)(ws + OFF_KC);
    short* vc   = (short*)(ws + OFF_VC);
    short* phc  = (short*)(ws + OFF_PHC);
    short* pic  = (short*)(ws + OFF_PIC);
    short* psc  = (short*)(ws + OFF_PSC);
    short* omc  = (short*)(ws + OFF_OMC);
    short* qwa  = (short*)(ws + OFF_QWA);
    short* qrh  = (short*)(ws + OFF_QRH);
    short* qsh  = (short*)(ws + OFF_QSH);
    short* kp   = (short*)(ws + OFF_KP);
    short* vt   = (short*)(ws + OFF_VT);
    short* qrs  = (short*)(ws + OFF_QR);
    float* ttd  = (float*)(ws + OFF_TTD);
    float* tts  = (float*)(ws + OFF_TTS);
    short* avec = (short*)(ws + OFF_AV);
    float* X    = (float*)(ws + OFF_X);

    conv_kernel<<<dim3(768, 1, 8), 256, 0, stream>>>(query, key, value, phi, pi_, psi, omega, rk,
                                                     qc, kc, vc, phc, pic, psc, omc, rkc);
    transpose_kernel<<<dim3(12, 12, 4), 256, 0, stream>>>(Wq, Wk, Wv, Wo, wqt, wkt, wvt, wot);
    qkv_kernel<<<dim3(16, 6, 3), 256, 0, stream>>>(qc, kc, vc, wqt, wkt, wvt,
                                                   bk, bv, rw, rr, rs, qwa, qrh, qsh, kp, vt);
    ttb_kernel<<<96, 256, 0, stream>>>(qsh, seg, ttd, tts);
    for (int nb = 0; nb < NHEAD; nb += 6) {
        qr_kernel<<<dim3(16, 6, 6), 256, 0, stream>>>(qrh, rkc, qrs, nb);
        flash_kernel<<<dim3(32, 6), 256, 0, stream>>>(qwa, kp, qrs, phc, pic, psc, omc, cls,
                                                      ttm, am, ttd, tts, vt, avec, nb);
    }
    outproj_kernel<<<dim3(16, 6), 256, 0, stream>>>(avec, wot, bo, query, X);
    ln_kernel<<<2048, 256, 0, stream>>>(X, lng, lnb, (float*)d_out);
}

// Round 4
// 1029.314 us; speedup vs baseline: 2.2941x; 2.2941x over previous
//
#include <hip/hip_runtime.h>
#include <hip/hip_bf16.h>
#include <stddef.h>

#define DEVINL __device__ __forceinline__

typedef __attribute__((ext_vector_type(8))) short short8;
typedef __attribute__((ext_vector_type(4))) float f32x4;

static constexpr int S_LEN = 2048;
static constexpr int C_LEN = 2048;
static constexpr int DMODEL = 768;
static constexpr int NHEAD = 12;
static constexpr int DHEAD = 64;
static constexpr float SCALE = 0.125f;   // 1/sqrt(64)

// ---------- bf16 helpers (bit-level, RNE) ----------
DEVINL float bf2f(short s) {
    union { unsigned u; float f; } v;
    v.u = ((unsigned)(unsigned short)s) << 16;
    return v.f;
}
DEVINL short f2bf(float f) {
    union { float f; unsigned u; } v;
    v.f = f;
    unsigned r = v.u + 0x7FFFu + ((v.u >> 16) & 1u);
    return (short)(r >> 16);
}
DEVINL f32x4 zero4() { f32x4 z; z[0]=0.f; z[1]=0.f; z[2]=0.f; z[3]=0.f; return z; }

// ---------- LDS XOR swizzle (T2): spread row-column slices across bank quads ----------
// element-index swizzle; keeps 16B alignment when col is a multiple of 8
DEVINL int swz(int width, int row, int col) {
    return (row * width + col) ^ ((row & 7) << 3);
}

// ---------- LDS staging: [ROWS][WIDTH] bf16 tile, 16B chunks, swizzled ----------
template<int ROWS, int WIDTH>
DEVINL void stage_tile(short* dst, const short* src, int src_stride) {
    constexpr int CPR = WIDTH / 8;           // 16B chunks per row
    constexpr int CH  = ROWS * CPR;
    for (int c = threadIdx.x; c < CH; c += 256) {
        int row = c / CPR;
        int cc  = (c % CPR) * 8;
        *(int4*)(dst + swz(WIDTH, row, cc)) = *(const int4*)(src + (size_t)row * src_stride + cc);
    }
}

// ---------- staging with elementwise product: dst[r][c] = a[r][c]*b[r][c], 64x64 bf16 ----------
DEVINL void stage_mul64(short* dst, const short* asrc, const short* bsrc) {
    for (int c = threadIdx.x; c < 512; c += 256) {
        int row = c >> 3;
        int cc  = (c & 7) * 8;
        short8 a = *(const short8*)(asrc + (size_t)row * DMODEL + cc);
        short8 b = *(const short8*)(bsrc + (size_t)row * DMODEL + cc);
        short8 r;
#pragma unroll
        for (int e = 0; e < 8; ++e) r[e] = f2bf(bf2f(a[e]) * bf2f(b[e]));
        *(short8*)(dst + swz(64, row, cc)) = r;
    }
}

// ---------- staging 128x64 with per-column f32 delta add: dst = src + (p1-p2)[col]*SCALE ----------
DEVINL void stage_addcol(short* dst, const short* src, const float* p1, const float* p2,
                         int col0, int src_stride) {
    for (int c = threadIdx.x; c < 1024; c += 256) {
        int row = c >> 3;
        int cc  = (c & 7) * 8;
        short8 a = *(const short8*)(src + (size_t)row * src_stride + cc);
        short8 r;
#pragma unroll
        for (int e = 0; e < 8; ++e)
            r[e] = f2bf(bf2f(a[e]) + (p1[col0 + cc + e] - p2[col0 + cc + e]) * SCALE);
        *(short8*)(dst + swz(64, row, cc)) = r;
    }
}

// ---------- one BK=64 MFMA step for a 128x128 tile, 4 waves in 2x2 of 64x64 ----------
DEVINL void mfma_step_128(const short* As, const short* Bs, f32x4 acc[4][4],
                          int wr, int wc, int lane) {
#pragma unroll
    for (int kk = 0; kk < 64; kk += 32) {
        short8 a[4], b[4];
#pragma unroll
        for (int mi = 0; mi < 4; ++mi)
            a[mi] = *(const short8*)(As + swz(64, wr*64 + mi*16 + (lane & 15), kk + (lane >> 4) * 8));
#pragma unroll
        for (int ni = 0; ni < 4; ++ni)
            b[ni] = *(const short8*)(Bs + swz(64, wc*64 + ni*16 + (lane & 15), kk + (lane >> 4) * 8));
#pragma unroll
        for (int mi = 0; mi < 4; ++mi)
#pragma unroll
            for (int ni = 0; ni < 4; ++ni)
                acc[mi][ni] = __builtin_amdgcn_mfma_f32_16x16x32_bf16(a[mi], b[ni], acc[mi][ni], 0, 0, 0);
    }
}

// ---------- one BK=64 MFMA step: wave computes 16 rows x 128 cols ----------
DEVINL void mfma_row16(const short* As, const short* Bs, f32x4 acc[8], int w, int lane) {
#pragma unroll
    for (int kk = 0; kk < 64; kk += 32) {
        short8 a = *(const short8*)(As + swz(64, w*16 + (lane & 15), kk + (lane >> 4) * 8));
#pragma unroll
        for (int nj = 0; nj < 8; ++nj) {
            short8 b = *(const short8*)(Bs + swz(64, nj*16 + (lane & 15), kk + (lane >> 4) * 8));
            acc[nj] = __builtin_amdgcn_mfma_f32_16x16x32_bf16(a, b, acc[nj], 0, 0, 0);
        }
    }
}

// ---------- shared 128x128 TN GEMM body (both strides 768, bf16 srcs) ----------
template<int KSTEPS>
DEVINL void gemm128_body(const short* A, const short* Bt, short* As, short* Bs,
                         f32x4 acc[4][4], int wr, int wc, int lane) {
    for (int ks = 0; ks < KSTEPS; ++ks) {
        if (ks) __syncthreads();
        stage_tile<128, 64>(As, A + ks * 64, DMODEL);
        stage_tile<128, 64>(Bs, Bt + ks * 64, DMODEL);
        __syncthreads();
        mfma_step_128(As, Bs, acc, wr, wc, lane);
    }
}

// ================= kernel A: f32 -> bf16 convert (8 streams via blockIdx.z) =================
__global__ void conv_kernel(const float* q, const float* k, const float* v,
                            const float* phi, const float* pi_, const float* psi,
                            const float* omega, const float* rk,
                            short* qc, short* kc, short* vc,
                            short* phc, short* pic, short* psc, short* omc, short* rkc) {
    int z = blockIdx.z;
    const float* src; short* dst; int n4;     // n4 = element count / 4
    switch (z) {
        case 0: src = q;     dst = qc;  n4 = 393216; break;
        case 1: src = k;     dst = kc;  n4 = 393216; break;
        case 2: src = v;     dst = vc;  n4 = 393216; break;
        case 3: src = phi;   dst = phc; n4 = 393216; break;
        case 4: src = pi_;   dst = pic; n4 = 393216; break;
        case 5: src = psi;   dst = psc; n4 = 393216; break;
        case 6: src = omega; dst = omc; n4 = 393216; break;
        default: src = rk;   dst = rkc; n4 = 147456; break;
    }
    for (int i = blockIdx.x * 256 + threadIdx.x; i < n4; i += gridDim.x * 256) {
        float4 f = *(const float4*)(src + (size_t)i * 4);
        short4 o;
        o.x = f2bf(f.x); o.y = f2bf(f.y); o.z = f2bf(f.z); o.w = f2bf(f.w);
        *(short4*)(dst + (size_t)i * 4) = o;
    }
}

// ================= kernel 0: transpose the 768x768 weights (f32 -> bf16^T) =================
__global__ void transpose_kernel(const float* wq, const float* wk, const float* wv, const float* wo,
                                 short* wqt, short* wkt, short* wvt, short* wot) {
    __shared__ float tile[64][65];
    int z = blockIdx.z;
    const float* src = (z == 0) ? wq : (z == 1) ? wk : (z == 2) ? wv : wo;
    short*       dst = (z == 0) ? wqt : (z == 1) ? wkt : (z == 2) ? wvt : wot;
    int r0 = blockIdx.x * 64, c0 = blockIdx.y * 64;
    for (int e = threadIdx.x; e < 4096; e += 256) {
        int rr = e >> 6, cc = e & 63;
        tile[rr][cc] = src[(size_t)(r0 + rr) * DMODEL + c0 + cc];
    }
    __syncthreads();
    for (int e = threadIdx.x; e < 4096; e += 256) {
        int rr = e >> 6, cc = e & 63;
        dst[(size_t)(c0 + rr) * DMODEL + r0 + cc] = f2bf(tile[cc][rr]);
    }
}

// ================= kernel 1: Q/K/V projections =================
__global__ __launch_bounds__(256, 2)
void qkv_kernel(const short* qc, const short* kc, const short* vc,
                const short* wqt, const short* wkt, const short* wvt,
                const float* bk, const float* bv, const float* rw,
                short* qw_a, short* kpack, short* vt) {
    __shared__ short As[128 * 64], Bs[128 * 64];
    int z = blockIdx.z;
    const short* A  = (z == 0) ? qc  : (z == 1) ? kc  : vc;
    const short* Bt = (z == 0) ? wqt : (z == 1) ? wkt : wvt;
    int i0 = blockIdx.x * 128, c0 = blockIdx.y * 128;
    int t = threadIdx.x, lane = t & 63, w = t >> 6, wr = w >> 1, wc = w & 1;

    f32x4 acc[4][4];
#pragma unroll
    for (int mi = 0; mi < 4; ++mi)
#pragma unroll
        for (int ni = 0; ni < 4; ++ni) acc[mi][ni] = zero4();

    gemm128_body<12>(A + (size_t)i0 * DMODEL, Bt + (size_t)c0 * DMODEL, As, Bs, acc, wr, wc, lane);

#pragma unroll
    for (int mi = 0; mi < 4; ++mi)
#pragma unroll
        for (int ni = 0; ni < 4; ++ni)
#pragma unroll
            for (int r = 0; r < 4; ++r) {
                int row = i0 + wr*64 + mi*16 + ((lane >> 4) << 2) + r;
                int col = c0 + wc*64 + ni*16 + (lane & 15);
                float v = acc[mi][ni][r];
                if (z == 0) {
                    // qwa = q*scale + rw*scale  (qr_hat/qs_hat derived later via deltas)
                    qw_a[(size_t)row * DMODEL + col] = f2bf(v * SCALE + rw[col] * SCALE);
                } else if (z == 1) {
                    float vv = v + bk[col];
                    kpack[((size_t)(col >> 6) * C_LEN + row) * DHEAD + (col & 63)] = f2bf(vv);
                } else {
                    float vv = v + bv[col];
                    vt[((size_t)(col >> 6) * DHEAD + (col & 63)) * C_LEN + row] = f2bf(vv);
                }
            }
}

// ================= kernel 2: qr slab for a 6-head chunk (A = qwa + (rr-rw)*scale) ==========
__global__ __launch_bounds__(256, 2)
void qr_kernel(const short* qwa, const short* rkc, const float* rr, const float* rw,
               short* qr, int n_base) {
    __shared__ short As[128 * 64], Bs[128 * 64];
    int nl = blockIdx.z, n = n_base + nl;
    int i0 = blockIdx.x * 128, d0 = blockIdx.y * 128;
    int t = threadIdx.x, lane = t & 63, w = t >> 6, wr = w >> 1, wc = w & 1;

    f32x4 acc[4][4];
#pragma unroll
    for (int mi = 0; mi < 4; ++mi)
#pragma unroll
        for (int ni = 0; ni < 4; ++ni) acc[mi][ni] = zero4();

    stage_addcol(As, qwa + (size_t)i0 * DMODEL + n * DHEAD, rr, rw, n * DHEAD, DMODEL);
    stage_tile<128, 64>(Bs, rkc + (size_t)d0 * DMODEL + n * DHEAD, DMODEL);
    __syncthreads();
    mfma_step_128(As, Bs, acc, wr, wc, lane);

#pragma unroll
    for (int mi = 0; mi < 4; ++mi)
#pragma unroll
        for (int ni = 0; ni < 4; ++ni)
#pragma unroll
            for (int r = 0; r < 4; ++r) {
                int row = i0 + wr*64 + mi*16 + ((lane >> 4) << 2) + r;   // i
                int col = d0 + wc*64 + ni*16 + (lane & 15);              // d
                qr[((size_t)nl * S_LEN + row) * DMODEL + col] = f2bf(acc[mi][ni][r]);
            }
}

// ================= kernel 2b: token-type bias (qs = qwa + (rs-rw)*scale) =================
__global__ void ttb_kernel(const short* qwa, const float* seg, const float* rs, const float* rw,
                           float* ttd, float* tts) {
    int idx = blockIdx.x * 256 + threadIdx.x;       // 12*2048 total
    int n = idx >> 11, i = idx & 2047;
    const short* q  = qwa + (size_t)i * DMODEL + n * DHEAD;
    const float* e0 = seg + n * DHEAD;              // seg[0][n][:]
    const float* e1 = seg + NHEAD * DHEAD + n * DHEAD;
    float s0 = 0.f, s1 = 0.f;
#pragma unroll
    for (int h = 0; h < DHEAD; ++h) {
        float qv = bf2f(q[h]) + (rs[n * DHEAD + h] - rw[n * DHEAD + h]) * SCALE;
        s0 += qv * e0[h];
        s1 += qv * e1[h];
    }
    ttd[n * S_LEN + i] = s0;
    tts[n * S_LEN + i] = s1;
}

// ================= kernel 3: fused score + softmax + PV, j-split partials =================
__global__ __launch_bounds__(256, 4)
void flash_kernel(const short* qw_a, const short* kpack, const short* qr,
                  const short* phc, const short* pic,
                  const short* psc, const short* omc, const float* cls_mask,
                  const int* ttmat, const int* amask, const float* ttd, const float* tts,
                  const short* vt, short* pacc, float* pm, float* pl, int n_base) {
    __shared__ short As[64 * 64];      // 8 KB
    __shared__ short Bs[128 * 64];     // 16 KB; reused as V^T [64][128] for PV
    __shared__ short Ps[64 * 128];     // 16 KB

    int nl = blockIdx.y, n = n_base + nl;
    int i0 = blockIdx.x * 64;
    int jz = blockIdx.z;               // 0..3, each handles 4 j-tiles of 128
    int t = threadIdx.x, lane = t & 63, w = t >> 6;
    int lrow = lane >> 4;       // 0..3
    int lcol = lane & 15;       // 0..15

    f32x4 out_acc[4];
    float m[4], l[4];
#pragma unroll
    for (int x = 0; x < 4; ++x) { out_acc[x] = zero4(); m[x] = -1.0e9f; l[x] = 0.f; }

    for (int jt = jz * 4; jt < jz * 4 + 4; ++jt) {
        int j0 = jt * 128;
        f32x4 acc_c[8], acc_p[8];
#pragma unroll
        for (int nj = 0; nj < 8; ++nj) { acc_c[nj] = zero4(); acc_p[nj] = zero4(); }

        // ---- content step (K = 64) ----
        __syncthreads();
        stage_tile<64, 64>(As, qw_a + (size_t)i0 * DMODEL + n * DHEAD, DMODEL);
        stage_tile<128, 64>(Bs, kpack + ((size_t)n * C_LEN + j0) * DHEAD, DHEAD);
        __syncthreads();
        mfma_row16(As, Bs, acc_c, w, lane);

        // ---- pos steps (K = 768 x {phi/psi} then {pi/omega}) ----
        for (int ks = 0; ks < 24; ++ks) {
            int d0 = (ks % 12) * 64;
            const short* qsrc = qr + ((size_t)nl * S_LEN + i0) * DMODEL + d0;
            const short* fsrc = ((ks < 12) ? phc : pic) + (size_t)i0 * DMODEL + d0;
            const short* bsrc = ((ks < 12) ? psc : omc) + (size_t)j0 * DMODEL + d0;
            __syncthreads();
            stage_mul64(As, qsrc, fsrc);
            stage_tile<128, 64>(Bs, bsrc, DMODEL);
            __syncthreads();
            mfma_row16(As, Bs, acc_p, w, lane);
        }

        // ---- epilogue: combine + online softmax ----
        int iBase = i0 + w*16 + lrow*4;
        float tdiff[4], tsame[4];
#pragma unroll
        for (int r = 0; r < 4; ++r) {
            tdiff[r] = ttd[n * S_LEN + iBase + r];
            tsame[r] = tts[n * S_LEN + iBase + r];
        }
        float pbuf[8][4];
        float tmax[4] = { -1.0e9f, -1.0e9f, -1.0e9f, -1.0e9f };
#pragma unroll
        for (int nj = 0; nj < 8; ++nj) {
            int jg = j0 + nj*16 + lcol;
            float pen = 1.0e6f * (1.0f - (float)amask[jg]);
#pragma unroll
            for (int r = 0; r < 4; ++r) {
                size_t eidx = (size_t)(iBase + r) * C_LEN + jg;
                float clsv = cls_mask[eidx];
                float ttv  = ttmat[eidx] ? tsame[r] : tdiff[r];
                float sc = acc_c[nj][r] + clsv * (acc_p[nj][r] + ttv) - pen;
                pbuf[nj][r] = sc;
                tmax[r] = fmaxf(tmax[r], sc);
            }
        }
        float alph[4];
#pragma unroll
        for (int r = 0; r < 4; ++r) {
            float v = tmax[r];
            v = fmaxf(v, __shfl_xor(v, 1));
            v = fmaxf(v, __shfl_xor(v, 2));
            v = fmaxf(v, __shfl_xor(v, 4));
            v = fmaxf(v, __shfl_xor(v, 8));
            float mn = fmaxf(m[r], v);
            alph[r] = __expf(fminf(m[r] - mn, 0.0f));
            m[r] = mn;
        }
        float rsum[4] = { 0.f, 0.f, 0.f, 0.f };
#pragma unroll
        for (int nj = 0; nj < 8; ++nj)
#pragma unroll
            for (int r = 0; r < 4; ++r) {
                float pv = __expf(fminf(pbuf[nj][r] - m[r], 0.0f));
                pbuf[nj][r] = pv;
                rsum[r] += pv;
            }
#pragma unroll
        for (int r = 0; r < 4; ++r) {
            float v = rsum[r];
            v += __shfl_xor(v, 1);
            v += __shfl_xor(v, 2);
            v += __shfl_xor(v, 4);
            v += __shfl_xor(v, 8);
            l[r] = l[r] * alph[r] + v;
        }
#pragma unroll
        for (int nh = 0; nh < 4; ++nh)
#pragma unroll
            for (int r = 0; r < 4; ++r) out_acc[nh][r] *= alph[r];

        // write P tile (bf16) to LDS (swizzled)
#pragma unroll
        for (int nj = 0; nj < 8; ++nj)
#pragma unroll
            for (int r = 0; r < 4; ++r)
                Ps[swz(128, w*16 + lrow*4 + r, nj*16 + lcol)] = f2bf(pbuf[nj][r]);

        // all waves done reading Bs (scores) and writing Ps
        __syncthreads();
        // stage V^T tile [64 h][128 j] into Bs region
        stage_tile<64, 128>(Bs, vt + (size_t)(n * DHEAD) * C_LEN + j0, C_LEN);
        __syncthreads();

        // ---- PV accumulate (K = 128) ----
#pragma unroll
        for (int kk = 0; kk < 4; ++kk) {
            short8 pa = *(const short8*)(Ps + swz(128, w*16 + lcol, kk*32 + lrow*8));
#pragma unroll
            for (int nh = 0; nh < 4; ++nh) {
                short8 vb = *(const short8*)(Bs + swz(128, nh*16 + lcol, kk*32 + lrow*8));
                out_acc[nh] = __builtin_amdgcn_mfma_f32_16x16x32_bf16(pa, vb, out_acc[nh], 0, 0, 0);
            }
        }
    }

    // ---- write partials (unnormalized): pacc[( (nl*2048+i)*4 + jz )*64 + h] ----
#pragma unroll
    for (int r = 0; r < 4; ++r) {
        int ig = i0 + w*16 + lrow*4 + r;
        size_t base = ((size_t)(nl * S_LEN + ig) * 4 + jz);
        if (lcol == 0) { pm[base] = m[r]; pl[base] = l[r]; }
#pragma unroll
        for (int nh = 0; nh < 4; ++nh)
            pacc[base * 64 + nh*16 + lcol] = f2bf(out_acc[nh][r]);
    }
}

// ================= kernel 3b: combine j-split partials -> avec =================
__global__ void combine_kernel(const short* pacc, const float* pm, const float* pl,
                               short* avec, int n_base) {
    int idx = blockIdx.x * 256 + threadIdx.x;   // 6*2048
    int nl = idx >> 11, i = idx & 2047;
    size_t b = (size_t)(nl * S_LEN + i) * 4;
    float m0 = pm[b], m1 = pm[b+1], m2 = pm[b+2], m3 = pm[b+3];
    float M = fmaxf(fmaxf(m0, m1), fmaxf(m2, m3));
    float w0 = __expf(m0 - M), w1 = __expf(m1 - M), w2 = __expf(m2 - M), w3 = __expf(m3 - M);
    float L = w0*pl[b] + w1*pl[b+1] + w2*pl[b+2] + w3*pl[b+3];
    float invL = 1.0f / L;
    const short* p = pacc + b * 64;
    short* o = avec + (size_t)i * DMODEL + (n_base + nl) * DHEAD;
    for (int h = 0; h < DHEAD; ++h) {
        float v = w0*bf2f(p[h]) + w1*bf2f(p[64+h]) + w2*bf2f(p[128+h]) + w3*bf2f(p[192+h]);
        o[h] = f2bf(v * invL);
    }
}

// ================= kernel 4: output projection + bias + residual =================
__global__ __launch_bounds__(256, 2)
void outproj_kernel(const short* avec, const short* wot, const float* bo,
                    const float* query, float* X) {
    __shared__ short As[128 * 64], Bs[128 * 64];
    int i0 = blockIdx.x * 128, c0 = blockIdx.y * 128;
    int t = threadIdx.x, lane = t & 63, w = t >> 6, wr = w >> 1, wc = w & 1;

    f32x4 acc[4][4];
#pragma unroll
    for (int mi = 0; mi < 4; ++mi)
#pragma unroll
        for (int ni = 0; ni < 4; ++ni) acc[mi][ni] = zero4();

    gemm128_body<12>(avec + (size_t)i0 * DMODEL, wot + (size_t)c0 * DMODEL, As, Bs, acc, wr, wc, lane);

#pragma unroll
    for (int mi = 0; mi < 4; ++mi)
#pragma unroll
        for (int ni = 0; ni < 4; ++ni)
#pragma unroll
            for (int r = 0; r < 4; ++r) {
                int row = i0 + wr*64 + mi*16 + ((lane >> 4) << 2) + r;
                int col = c0 + wc*64 + ni*16 + (lane & 15);
                float v = acc[mi][ni][r] + bo[col];
                X[(size_t)row * DMODEL + col] = v + query[(size_t)row * DMODEL + col];
            }
}

// ================= kernel 5: layernorm (f32 in, f32 out) =================
__global__ void ln_kernel(const float* X, const float* gam, const float* bet, float* out) {
    int row = blockIdx.x, t = threadIdx.x;
    const float* xr = X + (size_t)row * DMODEL;
    float x0 = xr[t], x1 = xr[t + 256], x2 = xr[t + 512];
    float s = x0 + x1 + x2;
    float q = x0*x0 + x1*x1 + x2*x2;
#pragma unroll
    for (int d = 1; d < 64; d <<= 1) { s += __shfl_xor(s, d); q += __shfl_xor(q, d); }
    __shared__ float rs_[4], rq_[4];
    int w = t >> 6, lane = t & 63;
    if (lane == 0) { rs_[w] = s; rq_[w] = q; }
    __syncthreads();
    s = rs_[0] + rs_[1] + rs_[2] + rs_[3];
    q = rq_[0] + rq_[1] + rq_[2] + rq_[3];
    float mu  = s * (1.0f / 768.0f);
    float var = q * (1.0f / 768.0f) - mu * mu;
    float rstd = rsqrtf(fmaxf(var, 0.0f) + 1e-9f);
    out[(size_t)row * DMODEL + t]       = (x0 - mu) * rstd * gam[t]       + bet[t];
    out[(size_t)row * DMODEL + t + 256] = (x1 - mu) * rstd * gam[t + 256] + bet[t + 256];
    out[(size_t)row * DMODEL + t + 512] = (x2 - mu) * rstd * gam[t + 512] + bet[t + 512];
}

// ================= launch =================
extern "C" void kernel_launch(void* const* d_in, const int* in_sizes, int n_in,
                              void* d_out, int out_size, void* d_ws, size_t ws_size,
                              hipStream_t stream) {
    const float* query = (const float*)d_in[0];
    const float* key   = (const float*)d_in[1];
    const float* value = (const float*)d_in[2];
    const float* phi   = (const float*)d_in[3];
    const float* pi_   = (const float*)d_in[4];
    const float* psi   = (const float*)d_in[5];
    const float* omega = (const float*)d_in[6];
    const float* cls   = (const float*)d_in[7];
    const int*   ttm   = (const int*)d_in[8];
    const int*   am    = (const int*)d_in[9];
    const float* Wq    = (const float*)d_in[10];
    const float* Wk    = (const float*)d_in[11];
    const float* bk    = (const float*)d_in[12];
    const float* Wv    = (const float*)d_in[13];
    const float* bv    = (const float*)d_in[14];
    const float* rw    = (const float*)d_in[15];
    const float* rr    = (const float*)d_in[16];
    const float* rk    = (const float*)d_in[17];
    const float* rs    = (const float*)d_in[18];
    const float* seg   = (const float*)d_in[19];
    const float* Wo    = (const float*)d_in[20];
    const float* bo    = (const float*)d_in[21];
    const float* lng   = (const float*)d_in[22];
    const float* lnb   = (const float*)d_in[23];

    char* ws = (char*)d_ws;
    constexpr size_t SZ_W   = 768ull * 768 * 2;
    constexpr size_t SZ_SD  = 2048ull * 768 * 2;
    constexpr size_t OFF_WQT = 0;
    constexpr size_t OFF_WKT = OFF_WQT + SZ_W;
    constexpr size_t OFF_WVT = OFF_WKT + SZ_W;
    constexpr size_t OFF_WOT = OFF_WVT + SZ_W;
    constexpr size_t OFF_RKC = OFF_WOT + SZ_W;
    constexpr size_t OFF_QC  = OFF_RKC + SZ_W;
    constexpr size_t OFF_KC  = OFF_QC  + SZ_SD;
    constexpr size_t OFF_VC  = OFF_KC  + SZ_SD;
    constexpr size_t OFF_PHC = OFF_VC  + SZ_SD;
    constexpr size_t OFF_PIC = OFF_PHC + SZ_SD;
    constexpr size_t OFF_PSC = OFF_PIC + SZ_SD;
    constexpr size_t OFF_OMC = OFF_PSC + SZ_SD;
    constexpr size_t OFF_QWA = OFF_OMC + SZ_SD;
    constexpr size_t OFF_KP  = OFF_QWA + SZ_SD;
    constexpr size_t OFF_VT  = OFF_KP  + SZ_SD;
    constexpr size_t OFF_QR  = OFF_VT  + SZ_SD;                 // 6-head slab, 18 MB
    constexpr size_t OFF_TTD = OFF_QR  + 6ull * 2048 * 768 * 2;
    constexpr size_t OFF_TTS = OFF_TTD + 12ull * 2048 * 4;
    constexpr size_t OFF_AV  = OFF_TTS + 12ull * 2048 * 4;
    // partial region: pacc bf16 [6][2048][4][64] + pm/pl f32 [6][2048][4]
    constexpr size_t OFF_PA  = OFF_AV  + SZ_SD;
    constexpr size_t OFF_PM  = OFF_PA  + 6ull * 2048 * 4 * 64 * 2;
    constexpr size_t OFF_PL  = OFF_PM  + 6ull * 2048 * 4 * 4;
    constexpr size_t OFF_X   = OFF_PA;                          // X aliases partials (dead by then)
    constexpr size_t NEED    = OFF_PL + 6ull * 2048 * 4 * 4;

    if (ws_size < NEED) return;   // diagnostic: leaves d_out untouched

    short* wqt  = (short*)(ws + OFF_WQT);
    short* wkt  = (short*)(ws + OFF_WKT);
    short* wvt  = (short*)(ws + OFF_WVT);
    short* wot  = (short*)(ws + OFF_WOT);
    short* rkc  = (short*)(ws + OFF_RKC);
    short* qc   = (short*)(ws + OFF_QC);
    short* kc   = (short*)(ws + OFF_KC);
    short* vc   = (short*)(ws + OFF_VC);
    short* phc  = (short*)(ws + OFF_PHC);
    short* pic  = (short*)(ws + OFF_PIC);
    short* psc  = (short*)(ws + OFF_PSC);
    short* omc  = (short*)(ws + OFF_OMC);
    short* qwa  = (short*)(ws + OFF_QWA);
    short* kp   = (short*)(ws + OFF_KP);
    short* vt   = (short*)(ws + OFF_VT);
    short* qrs  = (short*)(ws + OFF_QR);
    float* ttd  = (float*)(ws + OFF_TTD);
    float* tts  = (float*)(ws + OFF_TTS);
    short* avec = (short*)(ws + OFF_AV);
    short* pacc = (short*)(ws + OFF_PA);
    float* pm   = (float*)(ws + OFF_PM);
    float* pl   = (float*)(ws + OFF_PL);
    float* X    = (float*)(ws + OFF_X);

    conv_kernel<<<dim3(768, 1, 8), 256, 0, stream>>>(query, key, value, phi, pi_, psi, omega, rk,
                                                     qc, kc, vc, phc, pic, psc, omc, rkc);
    transpose_kernel<<<dim3(12, 12, 4), 256, 0, stream>>>(Wq, Wk, Wv, Wo, wqt, wkt, wvt, wot);
    qkv_kernel<<<dim3(16, 6, 3), 256, 0, stream>>>(qc, kc, vc, wqt, wkt, wvt,
                                                   bk, bv, rw, qwa, kp, vt);
    ttb_kernel<<<96, 256, 0, stream>>>(qwa, seg, rs, rw, ttd, tts);
    for (int nb = 0; nb < NHEAD; nb += 6) {
        qr_kernel<<<dim3(16, 6, 6), 256, 0, stream>>>(qwa, rkc, rr, rw, qrs, nb);
        flash_kernel<<<dim3(32, 6, 4), 256, 0, stream>>>(qwa, kp, qrs, phc, pic, psc, omc, cls,
                                                         ttm, am, ttd, tts, vt, pacc, pm, pl, nb);
        combine_kernel<<<48, 256, 0, stream>>>(pacc, pm, pl, avec, nb);
    }
    outproj_kernel<<<dim3(16, 6), 256, 0, stream>>>(avec, wot, bo, query, X);
    ln_kernel<<<2048, 256, 0, stream>>>(X, lng, lnb, (float*)d_out);
}

// Round 7
// 458.446 us; speedup vs baseline: 5.1507x; 2.2452x over previous
//
#include <hip/hip_runtime.h>
#include <hip/hip_bf16.h>
#include <stddef.h>

#define DEVINL __device__ __forceinline__

typedef __attribute__((ext_vector_type(8))) short short8;
typedef __attribute__((ext_vector_type(4))) float f32x4;

static constexpr int S_LEN = 2048;
static constexpr int C_LEN = 2048;
static constexpr int DMODEL = 768;
static constexpr int NHEAD = 12;
static constexpr int DHEAD = 64;
static constexpr float SCALE = 0.125f;   // 1/sqrt(64)

// ---------- bf16 helpers (bit-level, RNE) ----------
DEVINL float bf2f(short s) {
    union { unsigned u; float f; } v;
    v.u = ((unsigned)(unsigned short)s) << 16;
    return v.f;
}
DEVINL short f2bf(float f) {
    union { float f; unsigned u; } v;
    v.f = f;
    unsigned r = v.u + 0x7FFFu + ((v.u >> 16) & 1u);
    return (short)(r >> 16);
}
DEVINL f32x4 zero4() { f32x4 z; z[0]=0.f; z[1]=0.f; z[2]=0.f; z[3]=0.f; return z; }

// ---------- LDS XOR swizzle: elem-index XOR, 16B-granule, breaks column bank aliasing ----------
DEVINL int swz(int width, int row, int col) {
    return (row * width + col) ^ ((row & 7) << 3);
}

// ---------- async global->LDS staging, width 16, source pre-swizzled (rule #21) ----------
DEVINL void gl_lds16(const short* g, short* l) {
    __builtin_amdgcn_global_load_lds(
        (const __attribute__((address_space(1))) void*)g,
        (__attribute__((address_space(3))) void*)l,
        16, 0, 0);
}

// stage [ROWS][WIDTH] bf16 tile: LDS linear dest, global src address carries the swizzle.
// 256 threads = 4 waves; each global_load_lds call covers 64 lanes x 16B = 1KB.
template<int ROWS, int WIDTH>
DEVINL void stage_lds_swz(short* lds_tile, const short* src, int src_stride, int w, int lane) {
    constexpr int CPR = WIDTH / 8;             // 16B chunks per row
    constexpr int CH  = ROWS * CPR;
    for (int c0 = w * 64; c0 < CH; c0 += 256) {
        int chunk = c0 + lane;
        int row   = chunk / CPR;
        int ccol  = chunk % CPR;
        int scol  = ccol ^ (row & 7);          // inverse swizzle on the source
        gl_lds16(src + (size_t)row * src_stride + scol * 8, lds_tile + c0 * 8);
    }
}

// ---------- VALU staging (for compute-during-stage), swizzled writes ----------
DEVINL void stage_addcol(short* dst, const short* src, const float* p1, const float* p2,
                         int col0, int src_stride) {
    for (int c = threadIdx.x; c < 1024; c += 256) {
        int row = c >> 3;
        int cc  = (c & 7) * 8;
        short8 a = *(const short8*)(src + (size_t)row * src_stride + cc);
        short8 r;
#pragma unroll
        for (int e = 0; e < 8; ++e)
            r[e] = f2bf(bf2f(a[e]) + (p1[col0 + cc + e] - p2[col0 + cc + e]) * SCALE);
        *(short8*)(dst + swz(64, row, cc)) = r;
    }
}

// ---------- one BK=64 MFMA step for a 128x128 tile, 4 waves in 2x2 of 64x64 ----------
DEVINL void mfma_step_128(const short* As, const short* Bs, f32x4 acc[4][4],
                          int wr, int wc, int lane) {
#pragma unroll
    for (int kk = 0; kk < 64; kk += 32) {
        short8 a[4], b[4];
#pragma unroll
        for (int mi = 0; mi < 4; ++mi)
            a[mi] = *(const short8*)(As + swz(64, wr*64 + mi*16 + (lane & 15), kk + (lane >> 4) * 8));
#pragma unroll
        for (int ni = 0; ni < 4; ++ni)
            b[ni] = *(const short8*)(Bs + swz(64, wc*64 + ni*16 + (lane & 15), kk + (lane >> 4) * 8));
#pragma unroll
        for (int mi = 0; mi < 4; ++mi)
#pragma unroll
            for (int ni = 0; ni < 4; ++ni)
                acc[mi][ni] = __builtin_amdgcn_mfma_f32_16x16x32_bf16(a[mi], b[ni], acc[mi][ni], 0, 0, 0);
    }
}

// ---------- one BK=64 MFMA step: wave computes 16 rows x 128 cols ----------
DEVINL void mfma_row16(const short* As, const short* Bs, f32x4 acc[8], int w, int lane) {
#pragma unroll
    for (int kk = 0; kk < 64; kk += 32) {
        short8 a = *(const short8*)(As + swz(64, w*16 + (lane & 15), kk + (lane >> 4) * 8));
#pragma unroll
        for (int nj = 0; nj < 8; ++nj) {
            short8 b = *(const short8*)(Bs + swz(64, nj*16 + (lane & 15), kk + (lane >> 4) * 8));
            acc[nj] = __builtin_amdgcn_mfma_f32_16x16x32_bf16(a, b, acc[nj], 0, 0, 0);
        }
    }
}

// ---------- shared 128x128 TN GEMM body (both strides 768, bf16 srcs) ----------
template<int KSTEPS>
DEVINL void gemm128_body(const short* A, const short* Bt, short* As, short* Bs,
                         f32x4 acc[4][4], int wr, int wc, int lane, int w) {
    for (int ks = 0; ks < KSTEPS; ++ks) {
        if (ks) __syncthreads();
        stage_lds_swz<128, 64>(As, A + ks * 64, DMODEL, w, lane);
        stage_lds_swz<128, 64>(Bs, Bt + ks * 64, DMODEL, w, lane);
        __syncthreads();
        mfma_step_128(As, Bs, acc, wr, wc, lane);
    }
}

// ================= kernel A: f32 -> bf16 convert (6 streams via blockIdx.z) =================
__global__ void conv_kernel(const float* q, const float* k, const float* v,
                            const float* psi, const float* omega, const float* rk,
                            short* qc, short* kc, short* vc,
                            short* psc, short* omc, short* rkc) {
    int z = blockIdx.z;
    const float* src; short* dst; int n4;     // n4 = element count / 4
    switch (z) {
        case 0: src = q;     dst = qc;  n4 = 393216; break;
        case 1: src = k;     dst = kc;  n4 = 393216; break;
        case 2: src = v;     dst = vc;  n4 = 393216; break;
        case 3: src = psi;   dst = psc; n4 = 393216; break;
        case 4: src = omega; dst = omc; n4 = 393216; break;
        default: src = rk;   dst = rkc; n4 = 147456; break;
    }
    for (int i = blockIdx.x * 256 + threadIdx.x; i < n4; i += gridDim.x * 256) {
        float4 f = *(const float4*)(src + (size_t)i * 4);
        short4 o;
        o.x = f2bf(f.x); o.y = f2bf(f.y); o.z = f2bf(f.z); o.w = f2bf(f.w);
        *(short4*)(dst + (size_t)i * 4) = o;
    }
}

// ================= kernel 0: transpose the 768x768 weights (f32 -> bf16^T) =================
__global__ void transpose_kernel(const float* wq, const float* wk, const float* wv, const float* wo,
                                 short* wqt, short* wkt, short* wvt, short* wot) {
    __shared__ float tile[64][65];
    int z = blockIdx.z;
    const float* src = (z == 0) ? wq : (z == 1) ? wk : (z == 2) ? wv : wo;
    short*       dst = (z == 0) ? wqt : (z == 1) ? wkt : (z == 2) ? wvt : wot;
    int r0 = blockIdx.x * 64, c0 = blockIdx.y * 64;
    for (int e = threadIdx.x; e < 4096; e += 256) {
        int rr = e >> 6, cc = e & 63;
        tile[rr][cc] = src[(size_t)(r0 + rr) * DMODEL + c0 + cc];
    }
    __syncthreads();
    for (int e = threadIdx.x; e < 4096; e += 256) {
        int rr = e >> 6, cc = e & 63;
        dst[(size_t)(c0 + rr) * DMODEL + r0 + cc] = f2bf(tile[cc][rr]);
    }
}

// ================= kernel 1: Q/K/V projections =================
__global__ __launch_bounds__(256, 2)
void qkv_kernel(const short* qc, const short* kc, const short* vc,
                const short* wqt, const short* wkt, const short* wvt,
                const float* bk, const float* bv, const float* rw,
                short* qw_a, short* kpack, short* vt) {
    __shared__ short As[128 * 64], Bs[128 * 64];
    int z = blockIdx.z;
    const short* A  = (z == 0) ? qc  : (z == 1) ? kc  : vc;
    const short* Bt = (z == 0) ? wqt : (z == 1) ? wkt : wvt;
    int i0 = blockIdx.x * 128, c0 = blockIdx.y * 128;
    int t = threadIdx.x, lane = t & 63, w = t >> 6, wr = w >> 1, wc = w & 1;

    f32x4 acc[4][4];
#pragma unroll
    for (int mi = 0; mi < 4; ++mi)
#pragma unroll
        for (int ni = 0; ni < 4; ++ni) acc[mi][ni] = zero4();

    gemm128_body<12>(A + (size_t)i0 * DMODEL, Bt + (size_t)c0 * DMODEL, As, Bs, acc, wr, wc, lane, w);

#pragma unroll
    for (int mi = 0; mi < 4; ++mi)
#pragma unroll
        for (int ni = 0; ni < 4; ++ni)
#pragma unroll
            for (int r = 0; r < 4; ++r) {
                int row = i0 + wr*64 + mi*16 + ((lane >> 4) << 2) + r;
                int col = c0 + wc*64 + ni*16 + (lane & 15);
                float v = acc[mi][ni][r];
                if (z == 0) {
                    qw_a[(size_t)row * DMODEL + col] = f2bf(v * SCALE + rw[col] * SCALE);
                } else if (z == 1) {
                    float vv = v + bk[col];
                    kpack[((size_t)(col >> 6) * C_LEN + row) * DHEAD + (col & 63)] = f2bf(vv);
                } else {
                    float vv = v + bv[col];
                    vt[((size_t)(col >> 6) * DHEAD + (col & 63)) * C_LEN + row] = f2bf(vv);
                }
            }
}

// ====== kernel 2: qr GEMM for a 3-head chunk; epilogue writes a1=qr*phi, a2=qr*pi ======
__global__ __launch_bounds__(256, 2)
void qr_kernel(const short* qwa, const short* rkc, const float* rr, const float* rw,
               const float* phi, const float* pi_, short* a1, short* a2, int n_base) {
    __shared__ short As[128 * 64], Bs[128 * 64];
    int nl = blockIdx.z, n = n_base + nl;
    int i0 = blockIdx.x * 128, d0 = blockIdx.y * 128;
    int t = threadIdx.x, lane = t & 63, w = t >> 6, wr = w >> 1, wc = w & 1;

    f32x4 acc[4][4];
#pragma unroll
    for (int mi = 0; mi < 4; ++mi)
#pragma unroll
        for (int ni = 0; ni < 4; ++ni) acc[mi][ni] = zero4();

    stage_addcol(As, qwa + (size_t)i0 * DMODEL + n * DHEAD, rr, rw, n * DHEAD, DMODEL);
    stage_lds_swz<128, 64>(Bs, rkc + (size_t)d0 * DMODEL + n * DHEAD, DMODEL, w, lane);
    __syncthreads();
    mfma_step_128(As, Bs, acc, wr, wc, lane);

#pragma unroll
    for (int mi = 0; mi < 4; ++mi)
#pragma unroll
        for (int ni = 0; ni < 4; ++ni)
#pragma unroll
            for (int r = 0; r < 4; ++r) {
                int row = i0 + wr*64 + mi*16 + ((lane >> 4) << 2) + r;   // i
                int col = d0 + wc*64 + ni*16 + (lane & 15);              // d
                float v = acc[mi][ni][r];
                size_t src = (size_t)row * DMODEL + col;
                size_t dst = ((size_t)nl * S_LEN + row) * DMODEL + col;
                a1[dst] = f2bf(v * phi[src]);
                a2[dst] = f2bf(v * pi_[src]);
            }
}

// ================= kernel 2b: token-type bias (qs = qwa + (rs-rw)*scale) =================
__global__ void ttb_kernel(const short* qwa, const float* seg, const float* rs, const float* rw,
                           float* ttd, float* tts) {
    int idx = blockIdx.x * 256 + threadIdx.x;       // 12*2048 total
    int n = idx >> 11, i = idx & 2047;
    const short* q  = qwa + (size_t)i * DMODEL + n * DHEAD;
    const float* e0 = seg + n * DHEAD;
    const float* e1 = seg + NHEAD * DHEAD + n * DHEAD;
    float s0 = 0.f, s1 = 0.f;
#pragma unroll
    for (int h = 0; h < DHEAD; ++h) {
        float qv = bf2f(q[h]) + (rs[n * DHEAD + h] - rw[n * DHEAD + h]) * SCALE;
        s0 += qv * e0[h];
        s1 += qv * e1[h];
    }
    ttd[n * S_LEN + i] = s0;
    tts[n * S_LEN + i] = s1;
}

// ======= kernel 3: fused score + softmax-partial + PV; one 128-wide j-tile per block =======
__global__ __launch_bounds__(256, 4)
void flash_kernel(const short* qw_a, const short* kpack, const short* a1, const short* a2,
                  const short* psc, const short* omc, const float* cls_mask,
                  const int* ttmat, const int* amask, const float* ttd, const float* tts,
                  const short* vt, short* pacc, float* pm, float* pl, int n_base) {
    __shared__ short As[64 * 64];      // 8 KB
    __shared__ short Bs[128 * 64];     // 16 KB; reused as V^T [64][128] for PV
    __shared__ short Ps[64 * 128];     // 16 KB

    int nl = blockIdx.y, n = n_base + nl;
    int i0 = blockIdx.x * 64;
    int jt = blockIdx.z;               // 0..15
    int j0 = jt * 128;
    int t = threadIdx.x, lane = t & 63, w = t >> 6;
    int lrow = lane >> 4;       // 0..3
    int lcol = lane & 15;       // 0..15

    f32x4 acc_c[8], acc_p[8];
#pragma unroll
    for (int nj = 0; nj < 8; ++nj) { acc_c[nj] = zero4(); acc_p[nj] = zero4(); }

    // ---- content step (K = 64) ----
    stage_lds_swz<64, 64>(As, qw_a + (size_t)i0 * DMODEL + n * DHEAD, DMODEL, w, lane);
    stage_lds_swz<128, 64>(Bs, kpack + ((size_t)n * C_LEN + j0) * DHEAD, DHEAD, w, lane);
    __syncthreads();
    mfma_row16(As, Bs, acc_c, w, lane);

    // ---- pos steps (K = 768 x {a1/psi} then {a2/omega}) ----
    for (int ks = 0; ks < 24; ++ks) {
        int d0 = (ks % 12) * 64;
        const short* asrc = ((ks < 12) ? a1 : a2) + ((size_t)nl * S_LEN + i0) * DMODEL + d0;
        const short* bsrc = ((ks < 12) ? psc : omc) + (size_t)j0 * DMODEL + d0;
        __syncthreads();
        stage_lds_swz<64, 64>(As, asrc, DMODEL, w, lane);
        stage_lds_swz<128, 64>(Bs, bsrc, DMODEL, w, lane);
        __syncthreads();
        mfma_row16(As, Bs, acc_p, w, lane);
    }

    // ---- epilogue: combine + single-tile softmax partial ----
    int iBase = i0 + w*16 + lrow*4;
    float tdiff[4], tsame[4];
#pragma unroll
    for (int r = 0; r < 4; ++r) {
        tdiff[r] = ttd[n * S_LEN + iBase + r];
        tsame[r] = tts[n * S_LEN + iBase + r];
    }
    float pbuf[8][4];
    float m[4] = { -1.0e9f, -1.0e9f, -1.0e9f, -1.0e9f };
#pragma unroll
    for (int nj = 0; nj < 8; ++nj) {
        int jg = j0 + nj*16 + lcol;
        float pen = 1.0e6f * (1.0f - (float)amask[jg]);
#pragma unroll
        for (int r = 0; r < 4; ++r) {
            size_t eidx = (size_t)(iBase + r) * C_LEN + jg;
            float clsv = cls_mask[eidx];
            float ttv  = ttmat[eidx] ? tsame[r] : tdiff[r];
            float sc = acc_c[nj][r] + clsv * (acc_p[nj][r] + ttv) - pen;
            pbuf[nj][r] = sc;
            m[r] = fmaxf(m[r], sc);
        }
    }
#pragma unroll
    for (int r = 0; r < 4; ++r) {
        float v = m[r];
        v = fmaxf(v, __shfl_xor(v, 1));
        v = fmaxf(v, __shfl_xor(v, 2));
        v = fmaxf(v, __shfl_xor(v, 4));
        v = fmaxf(v, __shfl_xor(v, 8));
        m[r] = v;
    }
    float l[4] = { 0.f, 0.f, 0.f, 0.f };
#pragma unroll
    for (int nj = 0; nj < 8; ++nj)
#pragma unroll
        for (int r = 0; r < 4; ++r) {
            float pv = __expf(fminf(pbuf[nj][r] - m[r], 0.0f));
            pbuf[nj][r] = pv;
            l[r] += pv;
        }
#pragma unroll
    for (int r = 0; r < 4; ++r) {
        float v = l[r];
        v += __shfl_xor(v, 1);
        v += __shfl_xor(v, 2);
        v += __shfl_xor(v, 4);
        v += __shfl_xor(v, 8);
        l[r] = v;
    }

    // write P tile (bf16) to LDS (swizzled VALU writes; Ps reads use same mapping)
#pragma unroll
    for (int nj = 0; nj < 8; ++nj)
#pragma unroll
        for (int r = 0; r < 4; ++r)
            Ps[swz(128, w*16 + lrow*4 + r, nj*16 + lcol)] = f2bf(pbuf[nj][r]);

    __syncthreads();     // Ps complete; Bs free
    stage_lds_swz<64, 128>(Bs, vt + (size_t)(n * DHEAD) * C_LEN + j0, C_LEN, w, lane);
    __syncthreads();

    // ---- PV (K = 128) ----
    f32x4 out_acc[4];
#pragma unroll
    for (int x = 0; x < 4; ++x) out_acc[x] = zero4();
#pragma unroll
    for (int kk = 0; kk < 4; ++kk) {
        short8 pa = *(const short8*)(Ps + swz(128, w*16 + lcol, kk*32 + lrow*8));
#pragma unroll
        for (int nh = 0; nh < 4; ++nh) {
            short8 vb = *(const short8*)(Bs + swz(128, nh*16 + lcol, kk*32 + lrow*8));
            out_acc[nh] = __builtin_amdgcn_mfma_f32_16x16x32_bf16(pa, vb, out_acc[nh], 0, 0, 0);
        }
    }

    // ---- write partials (unnormalized) ----
#pragma unroll
    for (int r = 0; r < 4; ++r) {
        int ig = i0 + w*16 + lrow*4 + r;
        size_t base = ((size_t)(nl * S_LEN + ig) * 16 + jt);
        if (lcol == 0) { pm[base] = m[r]; pl[base] = l[r]; }
#pragma unroll
        for (int nh = 0; nh < 4; ++nh)
            pacc[base * 64 + nh*16 + lcol] = f2bf(out_acc[nh][r]);
    }
}

// ================= kernel 3b: combine 16 j-partials -> avec =================
__global__ void combine_kernel(const short* pacc, const float* pm, const float* pl,
                               short* avec, int n_base) {
    int idx = blockIdx.x * 256 + threadIdx.x;   // 3*2048*8 threads
    int h8 = idx & 7;
    int rest = idx >> 3;
    int i  = rest & 2047;
    int nl = rest >> 11;
    size_t b = ((size_t)nl * S_LEN + i) * 16;
    float M = -1.0e30f;
#pragma unroll
    for (int p = 0; p < 16; ++p) M = fmaxf(M, pm[b + p]);
    float L = 0.f;
    float o[8] = {0.f,0.f,0.f,0.f,0.f,0.f,0.f,0.f};
#pragma unroll
    for (int p = 0; p < 16; ++p) {
        float wg = __expf(pm[b + p] - M);
        L += wg * pl[b + p];
        short8 v = *(const short8*)(pacc + (b + p) * 64 + h8 * 8);
#pragma unroll
        for (int e = 0; e < 8; ++e) o[e] += wg * bf2f(v[e]);
    }
    float invL = 1.0f / L;
    short8 r;
#pragma unroll
    for (int e = 0; e < 8; ++e) r[e] = f2bf(o[e] * invL);
    *(short8*)(avec + (size_t)i * DMODEL + (n_base + nl) * DHEAD + h8 * 8) = r;
}

// ================= kernel 4: output projection + bias + residual =================
__global__ __launch_bounds__(256, 2)
void outproj_kernel(const short* avec, const short* wot, const float* bo,
                    const float* query, float* X) {
    __shared__ short As[128 * 64], Bs[128 * 64];
    int i0 = blockIdx.x * 128, c0 = blockIdx.y * 128;
    int t = threadIdx.x, lane = t & 63, w = t >> 6, wr = w >> 1, wc = w & 1;

    f32x4 acc[4][4];
#pragma unroll
    for (int mi = 0; mi < 4; ++mi)
#pragma unroll
        for (int ni = 0; ni < 4; ++ni) acc[mi][ni] = zero4();

    gemm128_body<12>(avec + (size_t)i0 * DMODEL, wot + (size_t)c0 * DMODEL, As, Bs, acc, wr, wc, lane, w);

#pragma unroll
    for (int mi = 0; mi < 4; ++mi)
#pragma unroll
        for (int ni = 0; ni < 4; ++ni)
#pragma unroll
            for (int r = 0; r < 4; ++r) {
                int row = i0 + wr*64 + mi*16 + ((lane >> 4) << 2) + r;
                int col = c0 + wc*64 + ni*16 + (lane & 15);
                float v = acc[mi][ni][r] + bo[col];
                X[(size_t)row * DMODEL + col] = v + query[(size_t)row * DMODEL + col];
            }
}

// ================= kernel 5: layernorm (f32 in, f32 out) =================
__global__ void ln_kernel(const float* X, const float* gam, const float* bet, float* out) {
    int row = blockIdx.x, t = threadIdx.x;
    const float* xr = X + (size_t)row * DMODEL;
    float x0 = xr[t], x1 = xr[t + 256], x2 = xr[t + 512];
    float s = x0 + x1 + x2;
    float q = x0*x0 + x1*x1 + x2*x2;
#pragma unroll
    for (int d = 1; d < 64; d <<= 1) { s += __shfl_xor(s, d); q += __shfl_xor(q, d); }
    __shared__ float rs_[4], rq_[4];
    int w = t >> 6, lane = t & 63;
    if (lane == 0) { rs_[w] = s; rq_[w] = q; }
    __syncthreads();
    s = rs_[0] + rs_[1] + rs_[2] + rs_[3];
    q = rq_[0] + rq_[1] + rq_[2] + rq_[3];
    float mu  = s * (1.0f / 768.0f);
    float var = q * (1.0f / 768.0f) - mu * mu;
    float rstd = rsqrtf(fmaxf(var, 0.0f) + 1e-9f);
    out[(size_t)row * DMODEL + t]       = (x0 - mu) * rstd * gam[t]       + bet[t];
    out[(size_t)row * DMODEL + t + 256] = (x1 - mu) * rstd * gam[t + 256] + bet[t + 256];
    out[(size_t)row * DMODEL + t + 512] = (x2 - mu) * rstd * gam[t + 512] + bet[t + 512];
}

// ================= launch =================
extern "C" void kernel_launch(void* const* d_in, const int* in_sizes, int n_in,
                              void* d_out, int out_size, void* d_ws, size_t ws_size,
                              hipStream_t stream) {
    const float* query = (const float*)d_in[0];
    const float* key   = (const float*)d_in[1];
    const float* value = (const float*)d_in[2];
    const float* phi   = (const float*)d_in[3];
    const float* pi_   = (const float*)d_in[4];
    const float* psi   = (const float*)d_in[5];
    const float* omega = (const float*)d_in[6];
    const float* cls   = (const float*)d_in[7];
    const int*   ttm   = (const int*)d_in[8];
    const int*   am    = (const int*)d_in[9];
    const float* Wq    = (const float*)d_in[10];
    const float* Wk    = (const float*)d_in[11];
    const float* bk    = (const float*)d_in[12];
    const float* Wv    = (const float*)d_in[13];
    const float* bv    = (const float*)d_in[14];
    const float* rw    = (const float*)d_in[15];
    const float* rr    = (const float*)d_in[16];
    const float* rk    = (const float*)d_in[17];
    const float* rs    = (const float*)d_in[18];
    const float* seg   = (const float*)d_in[19];
    const float* Wo    = (const float*)d_in[20];
    const float* bo    = (const float*)d_in[21];
    const float* lng   = (const float*)d_in[22];
    const float* lnb   = (const float*)d_in[23];

    char* ws = (char*)d_ws;
    constexpr size_t SZ_W   = 768ull * 768 * 2;
    constexpr size_t SZ_SD  = 2048ull * 768 * 2;
    constexpr size_t SZ_3H  = 3ull * 2048 * 768 * 2;
    constexpr size_t OFF_WQT = 0;
    constexpr size_t OFF_WKT = OFF_WQT + SZ_W;
    constexpr size_t OFF_WVT = OFF_WKT + SZ_W;
    constexpr size_t OFF_WOT = OFF_WVT + SZ_W;
    constexpr size_t OFF_RKC = OFF_WOT + SZ_W;
    constexpr size_t OFF_QC  = OFF_RKC + SZ_W;
    constexpr size_t OFF_KC  = OFF_QC  + SZ_SD;
    constexpr size_t OFF_VC  = OFF_KC  + SZ_SD;
    constexpr size_t OFF_PSC = OFF_VC  + SZ_SD;
    constexpr size_t OFF_OMC = OFF_PSC + SZ_SD;
    constexpr size_t OFF_QWA = OFF_OMC + SZ_SD;
    constexpr size_t OFF_KP  = OFF_QWA + SZ_SD;
    constexpr size_t OFF_VT  = OFF_KP  + SZ_SD;
    constexpr size_t OFF_A1  = OFF_VT  + SZ_SD;
    constexpr size_t OFF_A2  = OFF_A1  + SZ_3H;
    constexpr size_t OFF_TTD = OFF_A2  + SZ_3H;
    constexpr size_t OFF_TTS = OFF_TTD + 12ull * 2048 * 4;
    constexpr size_t OFF_AV  = OFF_TTS + 12ull * 2048 * 4;
    // partial region: pacc bf16 [3][2048][16][64] + pm/pl f32 [3][2048][16]
    constexpr size_t OFF_PA  = OFF_AV  + SZ_SD;
    constexpr size_t OFF_PM  = OFF_PA  + 3ull * 2048 * 16 * 64 * 2;
    constexpr size_t OFF_PL  = OFF_PM  + 3ull * 2048 * 16 * 4;
    constexpr size_t OFF_X   = OFF_PA;                          // X aliases partials (dead by then)
    constexpr size_t NEED    = OFF_PL + 3ull * 2048 * 16 * 4;

    if (ws_size < NEED) return;   // diagnostic: leaves d_out untouched

    short* wqt  = (short*)(ws + OFF_WQT);
    short* wkt  = (short*)(ws + OFF_WKT);
    short* wvt  = (short*)(ws + OFF_WVT);
    short* wot  = (short*)(ws + OFF_WOT);
    short* rkc  = (short*)(ws + OFF_RKC);
    short* qc   = (short*)(ws + OFF_QC);
    short* kc   = (short*)(ws + OFF_KC);
    short* vc   = (short*)(ws + OFF_VC);
    short* psc  = (short*)(ws + OFF_PSC);
    short* omc  = (short*)(ws + OFF_OMC);
    short* qwa  = (short*)(ws + OFF_QWA);
    short* kp   = (short*)(ws + OFF_KP);
    short* vt   = (short*)(ws + OFF_VT);
    short* a1   = (short*)(ws + OFF_A1);
    short* a2   = (short*)(ws + OFF_A2);
    float* ttd  = (float*)(ws + OFF_TTD);
    float* tts  = (float*)(ws + OFF_TTS);
    short* avec = (short*)(ws + OFF_AV);
    short* pacc = (short*)(ws + OFF_PA);
    float* pm   = (float*)(ws + OFF_PM);
    float* pl   = (float*)(ws + OFF_PL);
    float* X    = (float*)(ws + OFF_X);

    conv_kernel<<<dim3(768, 1, 6), 256, 0, stream>>>(query, key, value, psi, omega, rk,
                                                     qc, kc, vc, psc, omc, rkc);
    transpose_kernel<<<dim3(12, 12, 4), 256, 0, stream>>>(Wq, Wk, Wv, Wo, wqt, wkt, wvt, wot);
    qkv_kernel<<<dim3(16, 6, 3), 256, 0, stream>>>(qc, kc, vc, wqt, wkt, wvt,
                                                   bk, bv, rw, qwa, kp, vt);
    ttb_kernel<<<96, 256, 0, stream>>>(qwa, seg, rs, rw, ttd, tts);
    for (int nb = 0; nb < NHEAD; nb += 3) {
        qr_kernel<<<dim3(16, 6, 3), 256, 0, stream>>>(qwa, rkc, rr, rw, phi, pi_, a1, a2, nb);
        flash_kernel<<<dim3(32, 3, 16), 256, 0, stream>>>(qwa, kp, a1, a2, psc, omc, cls,
                                                          ttm, am, ttd, tts, vt, pacc, pm, pl, nb);
        combine_kernel<<<192, 256, 0, stream>>>(pacc, pm, pl, avec, nb);
    }
    outproj_kernel<<<dim3(16, 6), 256, 0, stream>>>(avec, wot, bo, query, X);
    ln_kernel<<<2048, 256, 0, stream>>>(X, lng, lnb, (float*)d_out);
}